// Round 16
// baseline (360.334 us; speedup 1.0000x reference)
//
#include <hip/hip_runtime.h>
#include <hip/hip_bf16.h>

#define F 128
#define PROP_ITER 4

typedef unsigned short u16;
typedef unsigned int u32;
typedef __attribute__((ext_vector_type(8))) short bf16x8;
typedef __attribute__((ext_vector_type(4))) float f32x4;

__device__ __forceinline__ float softsign(float v) { return __fdividef(v, 1.0f + fabsf(v)); }
__device__ __forceinline__ float fsig(float v)  { return __fdividef(1.0f, 1.0f + __expf(-v)); }
__device__ __forceinline__ float ftanh(float v) { return 1.0f - __fdividef(2.0f, __expf(2.0f * v) + 1.0f); }
__device__ __forceinline__ u16 f2bf(float f) {            // RTNE f32 -> bf16
    union { float f; unsigned u; } v; v.f = f;
    unsigned r = v.u + 0x7FFF + ((v.u >> 16) & 1);
    return (u16)(r >> 16);
}
__device__ __forceinline__ float bf2f(u32 lo16) {
    union { unsigned u; float f; } v; v.u = lo16 << 16; return v.f;
}

// ----------------------------------------------------------------------------
// CSR build.
// ----------------------------------------------------------------------------
__global__ __launch_bounds__(256) void count_edges(const int* __restrict__ ei,
                                                   const float* __restrict__ ea,
                                                   const float* __restrict__ t,
                                                   int* __restrict__ deg, int E, int N) {
    int i = blockIdx.x * 256 + threadIdx.x;
    int tot = 2 * E + N;
    if (i >= tot) return;
    int dst; float f;
    if (i < E)            { dst = ei[E + i];   f = ea[i]; }
    else if (i < 2 * E)   { dst = ei[i - E];   f = ea[i - E]; }
    else                  { dst = i - 2 * E;   f = 1.0f; }
    if (f <= t[0]) atomicAdd(&deg[dst], 1);
}

__global__ __launch_bounds__(256) void scan_partial(const int* __restrict__ deg,
                                                    int* __restrict__ bsum, int N) {
    __shared__ int sred[256];
    int tid = threadIdx.x;
    int base = blockIdx.x * 2048 + tid * 8;
    int s = 0;
    #pragma unroll
    for (int i = 0; i < 8; i++) {
        int idx = base + i;
        if (idx < N) s += deg[idx];
    }
    sred[tid] = s;
    __syncthreads();
    for (int off = 128; off; off >>= 1) {
        if (tid < off) sred[tid] += sred[tid + off];
        __syncthreads();
    }
    if (tid == 0) bsum[blockIdx.x] = sred[0];
}

__global__ __launch_bounds__(256) void scan_bsum(int* __restrict__ bsum, int nb) {
    __shared__ int s[256];
    int tid = threadIdx.x;
    int v = (tid < nb) ? bsum[tid] : 0;
    s[tid] = v;
    __syncthreads();
    for (int off = 1; off < 256; off <<= 1) {
        int u = (tid >= off) ? s[tid - off] : 0;
        __syncthreads();
        s[tid] += u;
        __syncthreads();
    }
    if (tid < nb) bsum[tid] = s[tid] - v;   // exclusive
    if (tid == 255) bsum[nb] = s[255];      // grand total
}

__global__ __launch_bounds__(256) void scan_final(const int* __restrict__ deg,
                                                  const int* __restrict__ bsum,
                                                  int* __restrict__ row_ptr,
                                                  int* __restrict__ cursor,
                                                  int N, int nb) {
    __shared__ int sred[256];
    int tid = threadIdx.x;
    int base = blockIdx.x * 2048 + tid * 8;
    int vals[8];
    int s = 0;
    #pragma unroll
    for (int i = 0; i < 8; i++) {
        int idx = base + i;
        vals[i] = (idx < N) ? deg[idx] : 0;
        s += vals[i];
    }
    sred[tid] = s;
    __syncthreads();
    for (int off = 1; off < 256; off <<= 1) {
        int u = (tid >= off) ? sred[tid - off] : 0;
        __syncthreads();
        sred[tid] += u;
        __syncthreads();
    }
    int run = bsum[blockIdx.x] + sred[tid] - s;
    #pragma unroll
    for (int i = 0; i < 8; i++) {
        int idx = base + i;
        if (idx < N) { row_ptr[idx] = run; cursor[idx] = run; run += vals[i]; }
    }
    if (blockIdx.x == 0 && tid == 0) row_ptr[N] = bsum[nb];
}

__global__ __launch_bounds__(256) void scatter_edges(const int* __restrict__ ei,
                                                     const float* __restrict__ ea,
                                                     const float* __restrict__ t,
                                                     int* __restrict__ cursor,
                                                     int* __restrict__ col, int E, int N) {
    int i = blockIdx.x * 256 + threadIdx.x;
    int tot = 2 * E + N;
    if (i >= tot) return;
    int src, dst; float f;
    if (i < E)            { src = ei[i];      dst = ei[E + i]; f = ea[i]; }
    else if (i < 2 * E)   { src = ei[i];      dst = ei[i - E]; f = ea[i - E]; }
    else                  { src = i - 2 * E;  dst = src;       f = 1.0f; }
    if (f <= t[0]) {
        int p = atomicAdd(&cursor[dst], 1);
        col[p] = src;
    }
}

// ----------------------------------------------------------------------------
// One-time conversions / packing.
// ----------------------------------------------------------------------------
__global__ __launch_bounds__(256) void conv_x(const float* __restrict__ x,
                                              u16* __restrict__ h16,
                                              u16* __restrict__ x16, int n4) {
    int i = blockIdx.x * 256 + threadIdx.x;
    if (i >= n4) return;
    float4 v = reinterpret_cast<const float4*>(x)[i];
    ushort4 u; u.x = f2bf(v.x); u.y = f2bf(v.y); u.z = f2bf(v.z); u.w = f2bf(v.w);
    reinterpret_cast<ushort4*>(h16)[i] = u;
    reinterpret_cast<ushort4*>(x16)[i] = u;
}

__device__ __forceinline__ void pk_rm(const float* __restrict__ W, u16* __restrict__ pk,
                                      int i, int nk0) {
    int j = i & 7, l = (i >> 3) & 63;
    int rest = i >> 9;
    int k0 = rest % nk0, fb = rest / nk0;
    int K = nk0 * 32;
    pk[i] = f2bf(W[(size_t)(fb * 16 + (l & 15)) * K + k0 * 32 + (l >> 4) * 8 + j]);
}
__device__ __forceinline__ void pk_tr(const float* __restrict__ A, u16* __restrict__ pk,
                                      int i, int nk0, int stride) {
    int j = i & 7, l = (i >> 3) & 63;
    int rest = i >> 9;
    int k0 = rest % nk0, fb = rest / nk0;
    int row = fb * 16 + (l & 15);
    int kk = k0 * 32 + (l >> 4) * 8 + j;
    pk[i] = f2bf(A[(size_t)kk * stride + row]);
}

// All 7 weight packs + deg/pooled zero-fill in one launch.
// total = 174080 + N + G*128.
__global__ __launch_bounds__(256) void pack_all(const float* __restrict__ Wih,
                                                const float* __restrict__ Whh,
                                                const float* __restrict__ aiW1,
                                                const float* __restrict__ aiW2,
                                                const float* __restrict__ ajW,
                                                const float* __restrict__ gW1,
                                                const float* __restrict__ gW2,
                                                u16* __restrict__ pkWih, u16* __restrict__ pkWhh,
                                                u16* __restrict__ pkW1, u16* __restrict__ pkW2,
                                                u16* __restrict__ pkWj, u16* __restrict__ pkgW1,
                                                u16* __restrict__ pkgW2,
                                                int* __restrict__ deg, float* __restrict__ pooled,
                                                int N, int GF) {
    int i = blockIdx.x * 256 + threadIdx.x;
    if      (i < 49152)  pk_rm(Wih,  pkWih, i, 4);
    else if (i < 98304)  pk_rm(Whh,  pkWhh, i - 49152, 4);
    else if (i < 131072) pk_tr(aiW1, pkW1,  i - 98304, 8, 128);
    else if (i < 147456) pk_tr(aiW2, pkW2,  i - 131072, 4, 128);
    else if (i < 163840) pk_tr(ajW,  pkWj,  i - 147456, 4, 128);
    else if (i < 172032) pk_tr(gW1,  pkgW1, i - 163840, 4, 64);
    else if (i < 174080) pk_tr(gW2,  pkgW2, i - 172032, 2, 32);
    else if (i < 174080 + N) deg[i - 174080] = 0;
    else if (i < 174080 + N + GF) pooled[i - 174080 - N] = 0.f;
}

// ----------------------------------------------------------------------------
// Gate MLP phases from a staged 64x128 bf16 LDS tile (4-wave helper for the
// standalone iteration-0 gate). One internal __syncthreads.
// ----------------------------------------------------------------------------
__device__ __forceinline__ void gate_from_lds(const u16* smh, u16* s1,
                                              const u16* __restrict__ pkgW1,
                                              const float* __restrict__ gb1,
                                              const u16* __restrict__ pkgW2,
                                              const float* __restrict__ gb2,
                                              const float* __restrict__ gW3,
                                              const float* __restrict__ gb3,
                                              float* __restrict__ eg,
                                              int node0, int N, int tid) {
    int wave = tid >> 6, lane = tid & 63, r = lane & 15, g = lane >> 4;
    {   // L1: 128 -> 64
        int j = wave * 16 + r;
        f32x4 acc[4];
        #pragma unroll
        for (int ns = 0; ns < 4; ns++) acc[ns] = (f32x4){0, 0, 0, 0};
        #pragma unroll
        for (int k0 = 0; k0 < 4; k0++) {
            bf16x8 b = *reinterpret_cast<const bf16x8*>(pkgW1 + ((size_t)(wave * 4 + k0) * 64 + lane) * 8);
            int sc = (k0 * 4 + g) ^ (r & 7);
            #pragma unroll
            for (int ns = 0; ns < 4; ns++) {
                bf16x8 a = *reinterpret_cast<const bf16x8*>(smh + ((ns * 16 + r) * 16 + sc) * 8);
                acc[ns] = __builtin_amdgcn_mfma_f32_16x16x32_bf16(a, b, acc[ns], 0, 0, 0);
            }
        }
        float bb = gb1[j];
        #pragma unroll
        for (int ns = 0; ns < 4; ns++)
            #pragma unroll
            for (int q = 0; q < 4; q++) {
                int row = ns * 16 + 4 * g + q;
                s1[(row * 8 + ((j >> 3) ^ (row & 7))) * 8 + (j & 7)] = f2bf(softsign(acc[ns][q] + bb));
            }
    }
    __syncthreads();
    {   // L2 (64->32) + L3 (32->1, shuffle reduce)
        int ns = wave;
        float partial[4] = {0.f, 0.f, 0.f, 0.f};
        #pragma unroll
        for (int fsub = 0; fsub < 2; fsub++) {
            f32x4 acc = {0, 0, 0, 0};
            #pragma unroll
            for (int k0 = 0; k0 < 2; k0++) {
                bf16x8 b = *reinterpret_cast<const bf16x8*>(pkgW2 + ((size_t)(fsub * 2 + k0) * 64 + lane) * 8);
                int sc = (k0 * 4 + g) ^ (r & 7);
                bf16x8 a = *reinterpret_cast<const bf16x8*>(s1 + ((ns * 16 + r) * 8 + sc) * 8);
                acc = __builtin_amdgcn_mfma_f32_16x16x32_bf16(a, b, acc, 0, 0, 0);
            }
            float bb = gb2[fsub * 16 + r];
            float w3 = gW3[fsub * 16 + r];
            #pragma unroll
            for (int q = 0; q < 4; q++) partial[q] += softsign(acc[q] + bb) * w3;
        }
        #pragma unroll
        for (int o = 1; o < 16; o <<= 1)
            #pragma unroll
            for (int q = 0; q < 4; q++) partial[q] += __shfl_xor(partial[q], o);
        if (r == 0) {
            #pragma unroll
            for (int q = 0; q < 4; q++) {
                int node = node0 + ns * 16 + 4 * g + q;
                if (node < N) eg[node] = __expf(partial[q] + gb3[0]);
            }
        }
    }
}

// ----------------------------------------------------------------------------
// Standalone gate (iteration 0): stage h -> gate_from_lds.
// ----------------------------------------------------------------------------
__global__ __launch_bounds__(256) void gate_mfma(const u16* __restrict__ h16,
                                                 const u16* __restrict__ pkgW1,
                                                 const float* __restrict__ gb1,
                                                 const u16* __restrict__ pkgW2,
                                                 const float* __restrict__ gb2,
                                                 const float* __restrict__ gW3,
                                                 const float* __restrict__ gb3,
                                                 float* __restrict__ eg, int N) {
    __shared__ __align__(16) u16 smh[64 * 128];
    __shared__ __align__(16) u16 s1[64 * 64];
    int tid = threadIdx.x;
    int node0 = blockIdx.x * 64;
    #pragma unroll
    for (int rr = 0; rr < 4; rr++) {
        int row = rr * 16 + (tid >> 4);
        int c = tid & 15;
        int gn = node0 + row; if (gn >= N) gn = N - 1;
        bf16x8 vh = *reinterpret_cast<const bf16x8*>(h16 + (size_t)gn * F + c * 8);
        *reinterpret_cast<bf16x8*>(smh + (row * 16 + (c ^ (row & 7))) * 8) = vh;
    }
    __syncthreads();
    gate_from_lds(smh, s1, pkgW1, gb1, pkgW2, gb2, gW3, gb3, eg, node0, N, tid);
}

// ----------------------------------------------------------------------------
// Softmax aggregation, single pass. 4 dst nodes per 256-thread block:
// wave w owns dst node0+w (4 lane-groups x 16 lanes walk its edges).
// 4x fewer blocks than the 1-dst version -> less dispatch ramp.
// ----------------------------------------------------------------------------
__global__ __launch_bounds__(256) void aggregate(const u16* __restrict__ h16,
                                                 const float* __restrict__ eg,
                                                 const int* __restrict__ row_ptr,
                                                 const int* __restrict__ col,
                                                 u16* __restrict__ m16, int N) {
    int tid = threadIdx.x;
    int wave = tid >> 6, lane = tid & 63;
    int dst = blockIdx.x * 4 + wave;
    if (dst >= N) return;
    int e0 = row_ptr[dst], e1 = row_ptr[dst + 1];
    int g4 = lane >> 4, r = lane & 15;
    float acc[8];
    #pragma unroll
    for (int i = 0; i < 8; i++) acc[i] = 0.f;
    float denom = 0.f;
    for (int e = e0 + g4; e < e1; e += 4) {
        int s = col[e];
        float w = eg[s];
        denom += w;
        bf16x8 hv = *reinterpret_cast<const bf16x8*>(h16 + (size_t)s * F + r * 8);
        #pragma unroll
        for (int i = 0; i < 8; i++) acc[i] += w * bf2f((u32)(u16)hv[i]);
    }
    #pragma unroll
    for (int o = 16; o <= 32; o <<= 1) {
        denom += __shfl_xor(denom, o);
        #pragma unroll
        for (int i = 0; i < 8; i++) acc[i] += __shfl_xor(acc[i], o);
    }
    if (g4 == 0) {
        float inv = __fdividef(1.0f, denom);   // self-loop guarantees denom > 0
        u32 w0 = (u32)f2bf(acc[0] * inv) | ((u32)f2bf(acc[1] * inv) << 16);
        u32 w1 = (u32)f2bf(acc[2] * inv) | ((u32)f2bf(acc[3] * inv) << 16);
        u32 w2 = (u32)f2bf(acc[4] * inv) | ((u32)f2bf(acc[5] * inv) << 16);
        u32 w3 = (u32)f2bf(acc[6] * inv) | ((u32)f2bf(acc[7] * inv) << 16);
        *reinterpret_cast<uint4*>(m16 + (size_t)dst * F + r * 8) = make_uint4(w0, w1, w2, w3);
    }
}

// ----------------------------------------------------------------------------
// GRU via MFMA + fused gate. 64 nodes/block, 8 waves, 2 LDS tiles (32 KB).
// ----------------------------------------------------------------------------
__global__ __launch_bounds__(512) void gru_fused(const u16* __restrict__ m16,
                                                 const u16* __restrict__ h16,
                                                 const u16* __restrict__ pkWih,
                                                 const u16* __restrict__ pkWhh,
                                                 const float* __restrict__ bih,
                                                 const float* __restrict__ bhh,
                                                 u16* __restrict__ h16o,
                                                 const u16* __restrict__ pkgW1,
                                                 const float* __restrict__ gb1,
                                                 const u16* __restrict__ pkgW2,
                                                 const float* __restrict__ gb2,
                                                 const float* __restrict__ gW3,
                                                 const float* __restrict__ gb3,
                                                 float* __restrict__ eg,
                                                 int do_gate, int N) {
    __shared__ __align__(16) u16 sm[64 * 128];    // m tile -> h_new tile
    __shared__ __align__(16) u16 sh[64 * 128];    // h tile -> gate s1 scratch
    int tid = threadIdx.x;
    int wave = tid >> 6, lane = tid & 63;
    int r = lane & 15, g = lane >> 4;
    int node0 = blockIdx.x * 64;

    #pragma unroll
    for (int rr = 0; rr < 2; rr++) {
        int row = rr * 32 + (tid >> 4);
        int c = tid & 15;
        int gn = node0 + row; if (gn >= N) gn = N - 1;
        bf16x8 vm = *reinterpret_cast<const bf16x8*>(m16 + (size_t)gn * F + c * 8);
        bf16x8 vh = *reinterpret_cast<const bf16x8*>(h16 + (size_t)gn * F + c * 8);
        int sc = c ^ (row & 7);
        *reinterpret_cast<bf16x8*>(sm + (row * 16 + sc) * 8) = vm;
        *reinterpret_cast<bf16x8*>(sh + (row * 16 + sc) * 8) = vh;
    }
    __syncthreads();

    {
        int fsub = wave;            // 8 waves cover all 8 fsubs
        f32x4 acc[4][4];            // [ns][r, z, ig, hg]
        #pragma unroll
        for (int ns = 0; ns < 4; ns++)
            #pragma unroll
            for (int c = 0; c < 4; c++) acc[ns][c] = (f32x4){0, 0, 0, 0};

        bf16x8 A0, A1, A2, A3, A4, A5, B0, B1, B2, B3, B4, B5;
        auto ld = [&](int k0, bf16x8& q0, bf16x8& q1, bf16x8& q2,
                      bf16x8& q3, bf16x8& q4, bf16x8& q5) {
            q0 = *reinterpret_cast<const bf16x8*>(pkWih + ((size_t)((0  + fsub) * 4 + k0) * 64 + lane) * 8);
            q1 = *reinterpret_cast<const bf16x8*>(pkWih + ((size_t)((8  + fsub) * 4 + k0) * 64 + lane) * 8);
            q2 = *reinterpret_cast<const bf16x8*>(pkWih + ((size_t)((16 + fsub) * 4 + k0) * 64 + lane) * 8);
            q3 = *reinterpret_cast<const bf16x8*>(pkWhh + ((size_t)((0  + fsub) * 4 + k0) * 64 + lane) * 8);
            q4 = *reinterpret_cast<const bf16x8*>(pkWhh + ((size_t)((8  + fsub) * 4 + k0) * 64 + lane) * 8);
            q5 = *reinterpret_cast<const bf16x8*>(pkWhh + ((size_t)((16 + fsub) * 4 + k0) * 64 + lane) * 8);
        };
        auto step = [&](int k0, const bf16x8& q0, const bf16x8& q1, const bf16x8& q2,
                        const bf16x8& q3, const bf16x8& q4, const bf16x8& q5) {
            int sc = (k0 * 4 + g) ^ (r & 7);
            #pragma unroll
            for (int ns = 0; ns < 4; ns++) {
                int rowb = (ns * 16 + r) * 16;
                bf16x8 am = *reinterpret_cast<const bf16x8*>(sm + (rowb + sc) * 8);
                bf16x8 ah = *reinterpret_cast<const bf16x8*>(sh + (rowb + sc) * 8);
                acc[ns][0] = __builtin_amdgcn_mfma_f32_16x16x32_bf16(am, q0, acc[ns][0], 0, 0, 0);
                acc[ns][0] = __builtin_amdgcn_mfma_f32_16x16x32_bf16(ah, q3, acc[ns][0], 0, 0, 0);
                acc[ns][1] = __builtin_amdgcn_mfma_f32_16x16x32_bf16(am, q1, acc[ns][1], 0, 0, 0);
                acc[ns][1] = __builtin_amdgcn_mfma_f32_16x16x32_bf16(ah, q4, acc[ns][1], 0, 0, 0);
                acc[ns][2] = __builtin_amdgcn_mfma_f32_16x16x32_bf16(am, q2, acc[ns][2], 0, 0, 0);
                acc[ns][3] = __builtin_amdgcn_mfma_f32_16x16x32_bf16(ah, q5, acc[ns][3], 0, 0, 0);
            }
        };
        ld(0, A0, A1, A2, A3, A4, A5);
        ld(1, B0, B1, B2, B3, B4, B5);
        step(0, A0, A1, A2, A3, A4, A5);
        ld(2, A0, A1, A2, A3, A4, A5);
        step(1, B0, B1, B2, B3, B4, B5);
        ld(3, B0, B1, B2, B3, B4, B5);
        step(2, A0, A1, A2, A3, A4, A5);
        step(3, B0, B1, B2, B3, B4, B5);

        __syncthreads();   // all k-loop reads of sm complete -> sm reusable

        int fj = fsub * 16 + r;
        int chunk = fj >> 3, e = fj & 7;
        float b_r  = bih[fj] + bhh[fj];
        float b_z  = bih[128 + fj] + bhh[128 + fj];
        float bi_g = bih[256 + fj];
        float bh_g = bhh[256 + fj];
        #pragma unroll
        for (int ns = 0; ns < 4; ns++) {
            #pragma unroll
            for (int q = 0; q < 4; q++) {
                int row = ns * 16 + 4 * g + q;
                float rr2 = fsig(acc[ns][0][q] + b_r);
                float z   = fsig(acc[ns][1][q] + b_z);
                float cand = ftanh(acc[ns][2][q] + bi_g + rr2 * (acc[ns][3][q] + bh_g));
                float hv = bf2f((u32)sh[(row * 16 + (chunk ^ (row & 7))) * 8 + e]);
                float hn = (1.0f - z) * cand + z * hv;
                sm[(row * 16 + (chunk ^ (row & 7))) * 8 + e] = f2bf(hn);   // h_new into sm
            }
        }
    }
    __syncthreads();   // h_new tile (sm) complete; sh blend reads done

    if (do_gate) {
        if (wave >= 4) {
            int tid2 = tid - 256;
            #pragma unroll
            for (int rr = 0; rr < 4; rr++) {
                int row = rr * 16 + (tid2 >> 4);
                int c = tid2 & 15;
                int gn = node0 + row;
                if (gn < N) {
                    bf16x8 v = *reinterpret_cast<const bf16x8*>(sm + (row * 16 + (c ^ (row & 7))) * 8);
                    *reinterpret_cast<bf16x8*>(h16o + (size_t)gn * F + c * 8) = v;
                }
            }
        } else {
            int j = wave * 16 + r;
            f32x4 acc[4];
            #pragma unroll
            for (int ns = 0; ns < 4; ns++) acc[ns] = (f32x4){0, 0, 0, 0};
            #pragma unroll
            for (int k0 = 0; k0 < 4; k0++) {
                bf16x8 b = *reinterpret_cast<const bf16x8*>(pkgW1 + ((size_t)(wave * 4 + k0) * 64 + lane) * 8);
                int sc = (k0 * 4 + g) ^ (r & 7);
                #pragma unroll
                for (int ns = 0; ns < 4; ns++) {
                    bf16x8 a = *reinterpret_cast<const bf16x8*>(sm + ((ns * 16 + r) * 16 + sc) * 8);
                    acc[ns] = __builtin_amdgcn_mfma_f32_16x16x32_bf16(a, b, acc[ns], 0, 0, 0);
                }
            }
            float bb = gb1[j];
            #pragma unroll
            for (int ns = 0; ns < 4; ns++)
                #pragma unroll
                for (int q = 0; q < 4; q++) {
                    int row = ns * 16 + 4 * g + q;
                    sh[(row * 8 + ((j >> 3) ^ (row & 7))) * 8 + (j & 7)] = f2bf(softsign(acc[ns][q] + bb));
                }
        }
        __syncthreads();
        if (wave < 4) {
            int ns = wave;
            float partial[4] = {0.f, 0.f, 0.f, 0.f};
            #pragma unroll
            for (int fsub = 0; fsub < 2; fsub++) {
                f32x4 acc = {0, 0, 0, 0};
                #pragma unroll
                for (int k0 = 0; k0 < 2; k0++) {
                    bf16x8 b = *reinterpret_cast<const bf16x8*>(pkgW2 + ((size_t)(fsub * 2 + k0) * 64 + lane) * 8);
                    int sc = (k0 * 4 + g) ^ (r & 7);
                    bf16x8 a = *reinterpret_cast<const bf16x8*>(sh + ((ns * 16 + r) * 8 + sc) * 8);
                    acc = __builtin_amdgcn_mfma_f32_16x16x32_bf16(a, b, acc, 0, 0, 0);
                }
                float bb = gb2[fsub * 16 + r];
                float w3 = gW3[fsub * 16 + r];
                #pragma unroll
                for (int q = 0; q < 4; q++) partial[q] += softsign(acc[q] + bb) * w3;
            }
            #pragma unroll
            for (int o = 1; o < 16; o <<= 1)
                #pragma unroll
                for (int q = 0; q < 4; q++) partial[q] += __shfl_xor(partial[q], o);
            if (r == 0) {
                #pragma unroll
                for (int q = 0; q < 4; q++) {
                    int node = node0 + ns * 16 + 4 * g + q;
                    if (node < N) eg[node] = __expf(partial[q] + gb3[0]);
                }
            }
        }
    } else {
        #pragma unroll
        for (int rr = 0; rr < 2; rr++) {
            int row = rr * 32 + (tid >> 4);
            int c = tid & 15;
            int gn = node0 + row;
            if (gn < N) {
                bf16x8 v = *reinterpret_cast<const bf16x8*>(sm + (row * 16 + (c ^ (row & 7))) * 8);
                *reinterpret_cast<bf16x8*>(h16o + (size_t)gn * F + c * 8) = v;
            }
        }
    }
}

// ----------------------------------------------------------------------------
// Fused final attention + pooling, 64 nodes/block. (unchanged)
// ----------------------------------------------------------------------------
__global__ __launch_bounds__(256) void attn_fused(const u16* __restrict__ h16,
                                                  const u16* __restrict__ x16,
                                                  const u16* __restrict__ pkW1,  // 128 out, K=256
                                                  const float* __restrict__ b1,
                                                  const u16* __restrict__ pkW2,  // 128 out, K=128
                                                  const float* __restrict__ b2,
                                                  const u16* __restrict__ pkWj,  // 128 out, K=128
                                                  const float* __restrict__ bj,
                                                  float* __restrict__ pooled,
                                                  int N, int npg, int G) {
    __shared__ __align__(16) u16 smh[64 * 128];   // h -> ai1
    __shared__ __align__(16) u16 sx[64 * 128];
    __shared__ float s_v[64 * 128];               // col-XOR swizzled
    __shared__ float s_mx[64], s_sum[64];
    __shared__ float s_pool[2][128];
    int tid = threadIdx.x;
    int wave = tid >> 6, lane = tid & 63, r = lane & 15, g = lane >> 4;
    int node0 = blockIdx.x * 64;

    s_pool[tid >> 7][tid & 127] = 0.f;

    #pragma unroll
    for (int rr = 0; rr < 4; rr++) {
        int row = rr * 16 + (tid >> 4);
        int c = tid & 15;
        int gn = node0 + row; if (gn >= N) gn = N - 1;
        bf16x8 vh = *reinterpret_cast<const bf16x8*>(h16 + (size_t)gn * F + c * 8);
        bf16x8 vx = *reinterpret_cast<const bf16x8*>(x16 + (size_t)gn * F + c * 8);
        int sc = c ^ (row & 7);
        *reinterpret_cast<bf16x8*>(smh + (row * 16 + sc) * 8) = vh;
        *reinterpret_cast<bf16x8*>(sx + (row * 16 + sc) * 8) = vx;
    }
    __syncthreads();

    // phase1: ai1 = ss([h|x] W1 + b1) -> registers
    float v1[2][4][4];
    #pragma unroll
    for (int fs = 0; fs < 2; fs++) {
        int fsub = wave * 2 + fs;
        int j = fsub * 16 + r;
        f32x4 acc[4];
        #pragma unroll
        for (int ns = 0; ns < 4; ns++) acc[ns] = (f32x4){0, 0, 0, 0};
        #pragma unroll
        for (int k0 = 0; k0 < 8; k0++) {
            bf16x8 b = *reinterpret_cast<const bf16x8*>(pkW1 + ((size_t)(fsub * 8 + k0) * 64 + lane) * 8);
            const u16* As = (k0 < 4) ? smh : sx;
            int sc = ((k0 & 3) * 4 + g) ^ (r & 7);
            #pragma unroll
            for (int ns = 0; ns < 4; ns++) {
                bf16x8 a = *reinterpret_cast<const bf16x8*>(As + ((ns * 16 + r) * 16 + sc) * 8);
                acc[ns] = __builtin_amdgcn_mfma_f32_16x16x32_bf16(a, b, acc[ns], 0, 0, 0);
            }
        }
        float bb = b1[j];
        #pragma unroll
        for (int ns = 0; ns < 4; ns++)
            #pragma unroll
            for (int q = 0; q < 4; q++) v1[fs][ns][q] = softsign(acc[ns][q] + bb);
    }
    __syncthreads();

    #pragma unroll
    for (int fs = 0; fs < 2; fs++) {
        int j = (wave * 2 + fs) * 16 + r;
        #pragma unroll
        for (int ns = 0; ns < 4; ns++)
            #pragma unroll
            for (int q = 0; q < 4; q++) {
                int row = ns * 16 + 4 * g + q;
                smh[(row * 16 + ((j >> 3) ^ (row & 7))) * 8 + (j & 7)] = f2bf(v1[fs][ns][q]);
            }
    }
    __syncthreads();

    // phase2: v = ss(ai1 W2 + b2) -> s_v
    #pragma unroll
    for (int fs = 0; fs < 2; fs++) {
        int fsub = wave * 2 + fs;
        int j = fsub * 16 + r;
        f32x4 acc[4];
        #pragma unroll
        for (int ns = 0; ns < 4; ns++) acc[ns] = (f32x4){0, 0, 0, 0};
        #pragma unroll
        for (int k0 = 0; k0 < 4; k0++) {
            bf16x8 b = *reinterpret_cast<const bf16x8*>(pkW2 + ((size_t)(fsub * 4 + k0) * 64 + lane) * 8);
            int sc = (k0 * 4 + g) ^ (r & 7);
            #pragma unroll
            for (int ns = 0; ns < 4; ns++) {
                bf16x8 a = *reinterpret_cast<const bf16x8*>(smh + ((ns * 16 + r) * 16 + sc) * 8);
                acc[ns] = __builtin_amdgcn_mfma_f32_16x16x32_bf16(a, b, acc[ns], 0, 0, 0);
            }
        }
        float bb = b2[j];
        #pragma unroll
        for (int ns = 0; ns < 4; ns++)
            #pragma unroll
            for (int q = 0; q < 4; q++) {
                int row = ns * 16 + 4 * g + q;
                s_v[row * 128 + (j ^ ((row & 31) << 2))] = softsign(acc[ns][q] + bb);
            }
    }
    __syncthreads();

    {
        int row = tid >> 2, base = (tid & 3) * 32;
        int swz = (row & 31) << 2;
        float mx = -1e30f;
        #pragma unroll
        for (int i = 0; i < 32; i++) mx = fmaxf(mx, s_v[row * 128 + ((base + i) ^ swz)]);
        mx = fmaxf(mx, __shfl_xor(mx, 1));
        mx = fmaxf(mx, __shfl_xor(mx, 2));
        float sum = 0.f;
        #pragma unroll
        for (int i = 0; i < 32; i++) sum += __expf(s_v[row * 128 + ((base + i) ^ swz)] - mx);
        sum += __shfl_xor(sum, 1);
        sum += __shfl_xor(sum, 2);
        if ((tid & 3) == 0) { s_mx[row] = mx; s_sum[row] = sum; }
    }
    __syncthreads();

    // phase3
    int graph0 = node0 / npg;
    #pragma unroll
    for (int fs = 0; fs < 2; fs++) {
        int fsub = wave * 2 + fs;
        int j = fsub * 16 + r;
        f32x4 acc[4];
        #pragma unroll
        for (int ns = 0; ns < 4; ns++) acc[ns] = (f32x4){0, 0, 0, 0};
        #pragma unroll
        for (int k0 = 0; k0 < 4; k0++) {
            bf16x8 b = *reinterpret_cast<const bf16x8*>(pkWj + ((size_t)(fsub * 4 + k0) * 64 + lane) * 8);
            int sc = (k0 * 4 + g) ^ (r & 7);
            #pragma unroll
            for (int ns = 0; ns < 4; ns++) {
                bf16x8 a = *reinterpret_cast<const bf16x8*>(sx + ((ns * 16 + r) * 16 + sc) * 8);
                acc[ns] = __builtin_amdgcn_mfma_f32_16x16x32_bf16(a, b, acc[ns], 0, 0, 0);
            }
        }
        float bb = bj[j];
        float p0 = 0.f, p1 = 0.f;
        #pragma unroll
        for (int ns = 0; ns < 4; ns++)
            #pragma unroll
            for (int q = 0; q < 4; q++) {
                int row = ns * 16 + 4 * g + q;
                int node = node0 + row;
                if (node < N) {
                    float aj = softsign(acc[ns][q] + bb);
                    float vv = s_v[row * 128 + (j ^ ((row & 31) << 2))];
                    float attn = __fdividef(__expf(vv - s_mx[row]), s_sum[row]);
                    float val = attn * aj;
                    if (node / npg == graph0) p0 += val; else p1 += val;
                }
            }
        if (p0 != 0.f) atomicAdd(&s_pool[0][j], p0);
        if (p1 != 0.f) atomicAdd(&s_pool[1][j], p1);
    }
    __syncthreads();

    {
        int b_ = tid >> 7, colj = tid & 127;
        float v = s_pool[b_][colj];
        int gg = graph0 + b_;
        if (v != 0.f && gg < G) atomicAdd(&pooled[(size_t)gg * F + colj], v);
    }
}

// ----------------------------------------------------------------------------
// Out MLP (G blocks).
// ----------------------------------------------------------------------------
__global__ __launch_bounds__(128) void out_mlp(const float* __restrict__ pooled,
                                               const float* __restrict__ W1, const float* __restrict__ b1,
                                               const float* __restrict__ W2, const float* __restrict__ b2,
                                               const float* __restrict__ W3, const float* __restrict__ b3,
                                               float* __restrict__ out, int H1, int H2) {
    __shared__ float sp[128];
    __shared__ float s1[96];
    __shared__ float s2[64];
    int g = blockIdx.x, j = threadIdx.x;
    sp[j] = pooled[g * F + j];
    __syncthreads();
    if (j < H1) {
        float a = b1[j];
        for (int k = 0; k < 128; k++) a += sp[k] * W1[k * H1 + j];
        s1[j] = fmaxf(a, 0.f);
    }
    __syncthreads();
    if (j < H2) {
        float a = b2[j];
        for (int k = 0; k < H1; k++) a += s1[k] * W2[k * H2 + j];
        s2[j] = fmaxf(a, 0.f);
    }
    __syncthreads();
    if (j == 0) {
        float a = b3[0];
        for (int k = 0; k < H2; k++) a += s2[k] * W3[k];
        out[g] = a;
    }
}

// ----------------------------------------------------------------------------
extern "C" void kernel_launch(void* const* d_in, const int* in_sizes, int n_in,
                              void* d_out, int out_size, void* d_ws, size_t ws_size,
                              hipStream_t stream) {
    const float* x    = (const float*)d_in[0];
    const int*   ei   = (const int*)  d_in[1];
    const float* ea   = (const float*)d_in[2];
    const float* t    = (const float*)d_in[4];
    const float* gW1  = (const float*)d_in[5];
    const float* gb1  = (const float*)d_in[6];
    const float* gW2  = (const float*)d_in[7];
    const float* gb2  = (const float*)d_in[8];
    const float* gW3  = (const float*)d_in[9];
    const float* gb3  = (const float*)d_in[10];
    const float* Wih  = (const float*)d_in[11];
    const float* Whh  = (const float*)d_in[12];
    const float* bih  = (const float*)d_in[13];
    const float* bhh  = (const float*)d_in[14];
    const float* aiW1 = (const float*)d_in[15];
    const float* aib1 = (const float*)d_in[16];
    const float* aiW2 = (const float*)d_in[17];
    const float* aib2 = (const float*)d_in[18];
    const float* ajW  = (const float*)d_in[19];
    const float* ajb  = (const float*)d_in[20];
    const float* oW1  = (const float*)d_in[21];
    const float* ob1  = (const float*)d_in[22];
    const float* oW2  = (const float*)d_in[23];
    const float* ob2  = (const float*)d_in[24];
    const float* oW3  = (const float*)d_in[25];
    const float* ob3  = (const float*)d_in[26];
    float* out = (float*)d_out;

    const int N = in_sizes[0] / F;
    const int E = in_sizes[2];
    const int G = out_size;
    const int npg = N / G;
    const int H1 = 85, H2 = 64;
    const int Etot = 2 * E + N;

    char* w = (char*)d_ws;
    auto carve = [&](size_t bytes) {
        void* p = (void*)w;
        w += (bytes + 255) & ~(size_t)255;
        return p;
    };
    int*   deg     = (int*)  carve((size_t)N * 4);
    int*   row_ptr = (int*)  carve((size_t)(N + 1) * 4);
    int*   cursor  = (int*)  carve((size_t)N * 4);
    int*   bsum    = (int*)  carve((size_t)512 * 4);
    int*   col     = (int*)  carve((size_t)Etot * 4);
    float* eg      = (float*)carve((size_t)N * 4);
    u16*   m16     = (u16*)  carve((size_t)N * F * 2);
    u16*   h16A    = (u16*)  carve((size_t)N * F * 2);
    u16*   h16B    = (u16*)  carve((size_t)N * F * 2);
    u16*   x16     = (u16*)  carve((size_t)N * F * 2);
    u16*   pkWih   = (u16*)  carve((size_t)384 * F * 2);
    u16*   pkWhh   = (u16*)  carve((size_t)384 * F * 2);
    u16*   pkW1    = (u16*)  carve((size_t)128 * 256 * 2);
    u16*   pkW2    = (u16*)  carve((size_t)128 * 128 * 2);
    u16*   pkWj    = (u16*)  carve((size_t)128 * 128 * 2);
    u16*   pkgW1   = (u16*)  carve((size_t)64 * 128 * 2);
    u16*   pkgW2   = (u16*)  carve((size_t)32 * 64 * 2);
    float* pooled  = (float*)carve((size_t)G * F * 4);
    (void)ws_size; (void)n_in;

    // --- one-time packs + deg/pooled zero (single kernel) + x conversion ---
    int packTot = 174080 + N + G * F;
    pack_all<<<(packTot + 255) / 256, 256, 0, stream>>>(Wih, Whh, aiW1, aiW2, ajW, gW1, gW2,
                                                        pkWih, pkWhh, pkW1, pkW2, pkWj, pkgW1, pkgW2,
                                                        deg, pooled, N, G * F);
    int n4 = N * F / 4;
    conv_x<<<(n4 + 255) / 256, 256, 0, stream>>>(x, h16A, x16, n4);

    // --- CSR build (hierarchical scan) ---
    int eb = (Etot + 255) / 256;
    count_edges<<<eb, 256, 0, stream>>>(ei, ea, t, deg, E, N);
    int nbs = (N + 2047) / 2048;   // <= 256 for N <= 524288
    scan_partial<<<nbs, 256, 0, stream>>>(deg, bsum, N);
    scan_bsum<<<1, 256, 0, stream>>>(bsum, nbs);
    scan_final<<<nbs, 256, 0, stream>>>(deg, bsum, row_ptr, cursor, N, nbs);
    scatter_edges<<<eb, 256, 0, stream>>>(ei, ea, t, cursor, col, E, N);

    u16* h16c = h16A;
    u16* h16n = h16B;
    int nb64 = (N + 63) / 64;

    // gate for iteration 0 (h0 = x)
    gate_mfma<<<nb64, 256, 0, stream>>>(h16c, pkgW1, gb1, pkgW2, gb2, gW3, gb3, eg, N);

    for (int it = 0; it < PROP_ITER; it++) {
        aggregate<<<(N + 3) / 4, 256, 0, stream>>>(h16c, eg, row_ptr, col, m16, N);
        gru_fused<<<nb64, 512, 0, stream>>>(m16, h16c, pkWih, pkWhh, bih, bhh, h16n,
                                            pkgW1, gb1, pkgW2, gb2, gW3, gb3, eg,
                                            (it < PROP_ITER - 1) ? 1 : 0, N);
        u16* tmp = h16c; h16c = h16n; h16n = tmp;
    }

    // --- fused attention + pooling ---
    attn_fused<<<nb64, 256, 0, stream>>>(h16c, x16, pkW1, aib1, pkW2, aib2, pkWj, ajb,
                                         pooled, N, npg, G);
    out_mlp<<<G, 128, 0, stream>>>(pooled, oW1, ob1, oW2, ob2, oW3, ob3, out, H1, H2);
}

// Round 17
// 353.300 us; speedup vs baseline: 1.0199x; 1.0199x over previous
//
#include <hip/hip_runtime.h>
#include <hip/hip_bf16.h>

#define F 128
#define PROP_ITER 4

typedef unsigned short u16;
typedef unsigned int u32;
typedef __attribute__((ext_vector_type(8))) short bf16x8;
typedef __attribute__((ext_vector_type(4))) float f32x4;

__device__ __forceinline__ float softsign(float v) { return __fdividef(v, 1.0f + fabsf(v)); }
__device__ __forceinline__ float fsig(float v)  { return __fdividef(1.0f, 1.0f + __expf(-v)); }
__device__ __forceinline__ float ftanh(float v) { return 1.0f - __fdividef(2.0f, __expf(2.0f * v) + 1.0f); }
__device__ __forceinline__ u16 f2bf(float f) {            // RTNE f32 -> bf16
    union { float f; unsigned u; } v; v.f = f;
    unsigned r = v.u + 0x7FFF + ((v.u >> 16) & 1);
    return (u16)(r >> 16);
}
__device__ __forceinline__ float bf2f(u32 lo16) {
    union { unsigned u; float f; } v; v.u = lo16 << 16; return v.f;
}

// ----------------------------------------------------------------------------
// CSR build.
// ----------------------------------------------------------------------------
__global__ __launch_bounds__(256) void count_edges(const int* __restrict__ ei,
                                                   const float* __restrict__ ea,
                                                   const float* __restrict__ t,
                                                   int* __restrict__ deg, int E, int N) {
    int i = blockIdx.x * 256 + threadIdx.x;
    int tot = 2 * E + N;
    if (i >= tot) return;
    int dst; float f;
    if (i < E)            { dst = ei[E + i];   f = ea[i]; }
    else if (i < 2 * E)   { dst = ei[i - E];   f = ea[i - E]; }
    else                  { dst = i - 2 * E;   f = 1.0f; }
    if (f <= t[0]) atomicAdd(&deg[dst], 1);
}

__global__ __launch_bounds__(256) void scan_partial(const int* __restrict__ deg,
                                                    int* __restrict__ bsum, int N) {
    __shared__ int sred[256];
    int tid = threadIdx.x;
    int base = blockIdx.x * 2048 + tid * 8;
    int s = 0;
    #pragma unroll
    for (int i = 0; i < 8; i++) {
        int idx = base + i;
        if (idx < N) s += deg[idx];
    }
    sred[tid] = s;
    __syncthreads();
    for (int off = 128; off; off >>= 1) {
        if (tid < off) sred[tid] += sred[tid + off];
        __syncthreads();
    }
    if (tid == 0) bsum[blockIdx.x] = sred[0];
}

__global__ __launch_bounds__(256) void scan_bsum(int* __restrict__ bsum, int nb) {
    __shared__ int s[256];
    int tid = threadIdx.x;
    int v = (tid < nb) ? bsum[tid] : 0;
    s[tid] = v;
    __syncthreads();
    for (int off = 1; off < 256; off <<= 1) {
        int u = (tid >= off) ? s[tid - off] : 0;
        __syncthreads();
        s[tid] += u;
        __syncthreads();
    }
    if (tid < nb) bsum[tid] = s[tid] - v;   // exclusive
    if (tid == 255) bsum[nb] = s[255];      // grand total
}

__global__ __launch_bounds__(256) void scan_final(const int* __restrict__ deg,
                                                  const int* __restrict__ bsum,
                                                  int* __restrict__ row_ptr,
                                                  int* __restrict__ cursor,
                                                  int N, int nb) {
    __shared__ int sred[256];
    int tid = threadIdx.x;
    int base = blockIdx.x * 2048 + tid * 8;
    int vals[8];
    int s = 0;
    #pragma unroll
    for (int i = 0; i < 8; i++) {
        int idx = base + i;
        vals[i] = (idx < N) ? deg[idx] : 0;
        s += vals[i];
    }
    sred[tid] = s;
    __syncthreads();
    for (int off = 1; off < 256; off <<= 1) {
        int u = (tid >= off) ? sred[tid - off] : 0;
        __syncthreads();
        sred[tid] += u;
        __syncthreads();
    }
    int run = bsum[blockIdx.x] + sred[tid] - s;
    #pragma unroll
    for (int i = 0; i < 8; i++) {
        int idx = base + i;
        if (idx < N) { row_ptr[idx] = run; cursor[idx] = run; run += vals[i]; }
    }
    if (blockIdx.x == 0 && tid == 0) row_ptr[N] = bsum[nb];
}

__global__ __launch_bounds__(256) void scatter_edges(const int* __restrict__ ei,
                                                     const float* __restrict__ ea,
                                                     const float* __restrict__ t,
                                                     int* __restrict__ cursor,
                                                     int* __restrict__ col, int E, int N) {
    int i = blockIdx.x * 256 + threadIdx.x;
    int tot = 2 * E + N;
    if (i >= tot) return;
    int src, dst; float f;
    if (i < E)            { src = ei[i];      dst = ei[E + i]; f = ea[i]; }
    else if (i < 2 * E)   { src = ei[i];      dst = ei[i - E]; f = ea[i - E]; }
    else                  { src = i - 2 * E;  dst = src;       f = 1.0f; }
    if (f <= t[0]) {
        int p = atomicAdd(&cursor[dst], 1);
        col[p] = src;
    }
}

// ----------------------------------------------------------------------------
// One-time conversions / packing.
// ----------------------------------------------------------------------------
__global__ __launch_bounds__(256) void conv_x(const float* __restrict__ x,
                                              u16* __restrict__ h16,
                                              u16* __restrict__ x16, int n4) {
    int i = blockIdx.x * 256 + threadIdx.x;
    if (i >= n4) return;
    float4 v = reinterpret_cast<const float4*>(x)[i];
    ushort4 u; u.x = f2bf(v.x); u.y = f2bf(v.y); u.z = f2bf(v.z); u.w = f2bf(v.w);
    reinterpret_cast<ushort4*>(h16)[i] = u;
    reinterpret_cast<ushort4*>(x16)[i] = u;
}

__device__ __forceinline__ void pk_rm(const float* __restrict__ W, u16* __restrict__ pk,
                                      int i, int nk0) {
    int j = i & 7, l = (i >> 3) & 63;
    int rest = i >> 9;
    int k0 = rest % nk0, fb = rest / nk0;
    int K = nk0 * 32;
    pk[i] = f2bf(W[(size_t)(fb * 16 + (l & 15)) * K + k0 * 32 + (l >> 4) * 8 + j]);
}
__device__ __forceinline__ void pk_tr(const float* __restrict__ A, u16* __restrict__ pk,
                                      int i, int nk0, int stride) {
    int j = i & 7, l = (i >> 3) & 63;
    int rest = i >> 9;
    int k0 = rest % nk0, fb = rest / nk0;
    int row = fb * 16 + (l & 15);
    int kk = k0 * 32 + (l >> 4) * 8 + j;
    pk[i] = f2bf(A[(size_t)kk * stride + row]);
}

// All 7 weight packs + deg/pooled zero-fill in one launch.
__global__ __launch_bounds__(256) void pack_all(const float* __restrict__ Wih,
                                                const float* __restrict__ Whh,
                                                const float* __restrict__ aiW1,
                                                const float* __restrict__ aiW2,
                                                const float* __restrict__ ajW,
                                                const float* __restrict__ gW1,
                                                const float* __restrict__ gW2,
                                                u16* __restrict__ pkWih, u16* __restrict__ pkWhh,
                                                u16* __restrict__ pkW1, u16* __restrict__ pkW2,
                                                u16* __restrict__ pkWj, u16* __restrict__ pkgW1,
                                                u16* __restrict__ pkgW2,
                                                int* __restrict__ deg, float* __restrict__ pooled,
                                                int N, int GF) {
    int i = blockIdx.x * 256 + threadIdx.x;
    if      (i < 49152)  pk_rm(Wih,  pkWih, i, 4);
    else if (i < 98304)  pk_rm(Whh,  pkWhh, i - 49152, 4);
    else if (i < 131072) pk_tr(aiW1, pkW1,  i - 98304, 8, 128);
    else if (i < 147456) pk_tr(aiW2, pkW2,  i - 131072, 4, 128);
    else if (i < 163840) pk_tr(ajW,  pkWj,  i - 147456, 4, 128);
    else if (i < 172032) pk_tr(gW1,  pkgW1, i - 163840, 4, 64);
    else if (i < 174080) pk_tr(gW2,  pkgW2, i - 172032, 2, 32);
    else if (i < 174080 + N) deg[i - 174080] = 0;
    else if (i < 174080 + N + GF) pooled[i - 174080 - N] = 0.f;
}

// ----------------------------------------------------------------------------
// Gate MLP phases from a staged 64x128 bf16 LDS tile (4-wave helper).
// ----------------------------------------------------------------------------
__device__ __forceinline__ void gate_from_lds(const u16* smh, u16* s1,
                                              const u16* __restrict__ pkgW1,
                                              const float* __restrict__ gb1,
                                              const u16* __restrict__ pkgW2,
                                              const float* __restrict__ gb2,
                                              const float* __restrict__ gW3,
                                              const float* __restrict__ gb3,
                                              float* __restrict__ eg,
                                              int node0, int N, int tid) {
    int wave = tid >> 6, lane = tid & 63, r = lane & 15, g = lane >> 4;
    {   // L1: 128 -> 64
        int j = wave * 16 + r;
        f32x4 acc[4];
        #pragma unroll
        for (int ns = 0; ns < 4; ns++) acc[ns] = (f32x4){0, 0, 0, 0};
        #pragma unroll
        for (int k0 = 0; k0 < 4; k0++) {
            bf16x8 b = *reinterpret_cast<const bf16x8*>(pkgW1 + ((size_t)(wave * 4 + k0) * 64 + lane) * 8);
            int sc = (k0 * 4 + g) ^ (r & 7);
            #pragma unroll
            for (int ns = 0; ns < 4; ns++) {
                bf16x8 a = *reinterpret_cast<const bf16x8*>(smh + ((ns * 16 + r) * 16 + sc) * 8);
                acc[ns] = __builtin_amdgcn_mfma_f32_16x16x32_bf16(a, b, acc[ns], 0, 0, 0);
            }
        }
        float bb = gb1[j];
        #pragma unroll
        for (int ns = 0; ns < 4; ns++)
            #pragma unroll
            for (int q = 0; q < 4; q++) {
                int row = ns * 16 + 4 * g + q;
                s1[(row * 8 + ((j >> 3) ^ (row & 7))) * 8 + (j & 7)] = f2bf(softsign(acc[ns][q] + bb));
            }
    }
    __syncthreads();
    {   // L2 (64->32) + L3 (32->1, shuffle reduce)
        int ns = wave;
        float partial[4] = {0.f, 0.f, 0.f, 0.f};
        #pragma unroll
        for (int fsub = 0; fsub < 2; fsub++) {
            f32x4 acc = {0, 0, 0, 0};
            #pragma unroll
            for (int k0 = 0; k0 < 2; k0++) {
                bf16x8 b = *reinterpret_cast<const bf16x8*>(pkgW2 + ((size_t)(fsub * 2 + k0) * 64 + lane) * 8);
                int sc = (k0 * 4 + g) ^ (r & 7);
                bf16x8 a = *reinterpret_cast<const bf16x8*>(s1 + ((ns * 16 + r) * 8 + sc) * 8);
                acc = __builtin_amdgcn_mfma_f32_16x16x32_bf16(a, b, acc, 0, 0, 0);
            }
            float bb = gb2[fsub * 16 + r];
            float w3 = gW3[fsub * 16 + r];
            #pragma unroll
            for (int q = 0; q < 4; q++) partial[q] += softsign(acc[q] + bb) * w3;
        }
        #pragma unroll
        for (int o = 1; o < 16; o <<= 1)
            #pragma unroll
            for (int q = 0; q < 4; q++) partial[q] += __shfl_xor(partial[q], o);
        if (r == 0) {
            #pragma unroll
            for (int q = 0; q < 4; q++) {
                int node = node0 + ns * 16 + 4 * g + q;
                if (node < N) eg[node] = __expf(partial[q] + gb3[0]);
            }
        }
    }
}

// ----------------------------------------------------------------------------
// Standalone gate (iteration 0): stage h -> gate_from_lds.
// ----------------------------------------------------------------------------
__global__ __launch_bounds__(256) void gate_mfma(const u16* __restrict__ h16,
                                                 const u16* __restrict__ pkgW1,
                                                 const float* __restrict__ gb1,
                                                 const u16* __restrict__ pkgW2,
                                                 const float* __restrict__ gb2,
                                                 const float* __restrict__ gW3,
                                                 const float* __restrict__ gb3,
                                                 float* __restrict__ eg, int N) {
    __shared__ __align__(16) u16 smh[64 * 128];
    __shared__ __align__(16) u16 s1[64 * 64];
    int tid = threadIdx.x;
    int node0 = blockIdx.x * 64;
    #pragma unroll
    for (int rr = 0; rr < 4; rr++) {
        int row = rr * 16 + (tid >> 4);
        int c = tid & 15;
        int gn = node0 + row; if (gn >= N) gn = N - 1;
        bf16x8 vh = *reinterpret_cast<const bf16x8*>(h16 + (size_t)gn * F + c * 8);
        *reinterpret_cast<bf16x8*>(smh + (row * 16 + (c ^ (row & 7))) * 8) = vh;
    }
    __syncthreads();
    gate_from_lds(smh, s1, pkgW1, gb1, pkgW2, gb2, gW3, gb3, eg, node0, N, tid);
}

// ----------------------------------------------------------------------------
// Softmax aggregation, single pass, 4 dst/block, 2-deep unrolled edge loop
// (two independent accumulator chains -> 2x memory-level parallelism).
// ----------------------------------------------------------------------------
__global__ __launch_bounds__(256) void aggregate(const u16* __restrict__ h16,
                                                 const float* __restrict__ eg,
                                                 const int* __restrict__ row_ptr,
                                                 const int* __restrict__ col,
                                                 u16* __restrict__ m16, int N) {
    int tid = threadIdx.x;
    int wave = tid >> 6, lane = tid & 63;
    int dst = blockIdx.x * 4 + wave;
    if (dst >= N) return;
    int e0 = row_ptr[dst], e1 = row_ptr[dst + 1];
    int g4 = lane >> 4, r = lane & 15;
    float acc[8], acc2[8];
    #pragma unroll
    for (int i = 0; i < 8; i++) { acc[i] = 0.f; acc2[i] = 0.f; }
    float denom = 0.f, denom2 = 0.f;
    int e = e0 + g4;
    for (; e + 4 < e1; e += 8) {
        int s0 = col[e], s1 = col[e + 4];
        float w0 = eg[s0], w1 = eg[s1];
        bf16x8 h0 = *reinterpret_cast<const bf16x8*>(h16 + (size_t)s0 * F + r * 8);
        bf16x8 h1 = *reinterpret_cast<const bf16x8*>(h16 + (size_t)s1 * F + r * 8);
        denom += w0; denom2 += w1;
        #pragma unroll
        for (int i = 0; i < 8; i++) acc[i]  += w0 * bf2f((u32)(u16)h0[i]);
        #pragma unroll
        for (int i = 0; i < 8; i++) acc2[i] += w1 * bf2f((u32)(u16)h1[i]);
    }
    for (; e < e1; e += 4) {
        int s = col[e];
        float w = eg[s];
        denom += w;
        bf16x8 hv = *reinterpret_cast<const bf16x8*>(h16 + (size_t)s * F + r * 8);
        #pragma unroll
        for (int i = 0; i < 8; i++) acc[i] += w * bf2f((u32)(u16)hv[i]);
    }
    denom += denom2;
    #pragma unroll
    for (int i = 0; i < 8; i++) acc[i] += acc2[i];
    #pragma unroll
    for (int o = 16; o <= 32; o <<= 1) {
        denom += __shfl_xor(denom, o);
        #pragma unroll
        for (int i = 0; i < 8; i++) acc[i] += __shfl_xor(acc[i], o);
    }
    if (g4 == 0) {
        float inv = __fdividef(1.0f, denom);   // self-loop guarantees denom > 0
        u32 w0 = (u32)f2bf(acc[0] * inv) | ((u32)f2bf(acc[1] * inv) << 16);
        u32 w1 = (u32)f2bf(acc[2] * inv) | ((u32)f2bf(acc[3] * inv) << 16);
        u32 w2 = (u32)f2bf(acc[4] * inv) | ((u32)f2bf(acc[5] * inv) << 16);
        u32 w3 = (u32)f2bf(acc[6] * inv) | ((u32)f2bf(acc[7] * inv) << 16);
        *reinterpret_cast<uint4*>(m16 + (size_t)dst * F + r * 8) = make_uint4(w0, w1, w2, w3);
    }
}

// ----------------------------------------------------------------------------
// GRU via MFMA + fused gate. 64 nodes/block, 8 waves, 2 LDS tiles (32 KB).
// ----------------------------------------------------------------------------
__global__ __launch_bounds__(512) void gru_fused(const u16* __restrict__ m16,
                                                 const u16* __restrict__ h16,
                                                 const u16* __restrict__ pkWih,
                                                 const u16* __restrict__ pkWhh,
                                                 const float* __restrict__ bih,
                                                 const float* __restrict__ bhh,
                                                 u16* __restrict__ h16o,
                                                 const u16* __restrict__ pkgW1,
                                                 const float* __restrict__ gb1,
                                                 const u16* __restrict__ pkgW2,
                                                 const float* __restrict__ gb2,
                                                 const float* __restrict__ gW3,
                                                 const float* __restrict__ gb3,
                                                 float* __restrict__ eg,
                                                 int do_gate, int N) {
    __shared__ __align__(16) u16 sm[64 * 128];    // m tile -> h_new tile
    __shared__ __align__(16) u16 sh[64 * 128];    // h tile -> gate s1 scratch
    int tid = threadIdx.x;
    int wave = tid >> 6, lane = tid & 63;
    int r = lane & 15, g = lane >> 4;
    int node0 = blockIdx.x * 64;

    #pragma unroll
    for (int rr = 0; rr < 2; rr++) {
        int row = rr * 32 + (tid >> 4);
        int c = tid & 15;
        int gn = node0 + row; if (gn >= N) gn = N - 1;
        bf16x8 vm = *reinterpret_cast<const bf16x8*>(m16 + (size_t)gn * F + c * 8);
        bf16x8 vh = *reinterpret_cast<const bf16x8*>(h16 + (size_t)gn * F + c * 8);
        int sc = c ^ (row & 7);
        *reinterpret_cast<bf16x8*>(sm + (row * 16 + sc) * 8) = vm;
        *reinterpret_cast<bf16x8*>(sh + (row * 16 + sc) * 8) = vh;
    }
    __syncthreads();

    {
        int fsub = wave;
        f32x4 acc[4][4];   // [ns][r, z, ig, hg]
        #pragma unroll
        for (int ns = 0; ns < 4; ns++)
            #pragma unroll
            for (int c = 0; c < 4; c++) acc[ns][c] = (f32x4){0, 0, 0, 0};

        bf16x8 A0, A1, A2, A3, A4, A5, B0, B1, B2, B3, B4, B5;
        auto ld = [&](int k0, bf16x8& q0, bf16x8& q1, bf16x8& q2,
                      bf16x8& q3, bf16x8& q4, bf16x8& q5) {
            q0 = *reinterpret_cast<const bf16x8*>(pkWih + ((size_t)((0  + fsub) * 4 + k0) * 64 + lane) * 8);
            q1 = *reinterpret_cast<const bf16x8*>(pkWih + ((size_t)((8  + fsub) * 4 + k0) * 64 + lane) * 8);
            q2 = *reinterpret_cast<const bf16x8*>(pkWih + ((size_t)((16 + fsub) * 4 + k0) * 64 + lane) * 8);
            q3 = *reinterpret_cast<const bf16x8*>(pkWhh + ((size_t)((0  + fsub) * 4 + k0) * 64 + lane) * 8);
            q4 = *reinterpret_cast<const bf16x8*>(pkWhh + ((size_t)((8  + fsub) * 4 + k0) * 64 + lane) * 8);
            q5 = *reinterpret_cast<const bf16x8*>(pkWhh + ((size_t)((16 + fsub) * 4 + k0) * 64 + lane) * 8);
        };
        auto step = [&](int k0, const bf16x8& q0, const bf16x8& q1, const bf16x8& q2,
                        const bf16x8& q3, const bf16x8& q4, const bf16x8& q5) {
            int sc = (k0 * 4 + g) ^ (r & 7);
            #pragma unroll
            for (int ns = 0; ns < 4; ns++) {
                int rowb = (ns * 16 + r) * 16;
                bf16x8 am = *reinterpret_cast<const bf16x8*>(sm + (rowb + sc) * 8);
                bf16x8 ah = *reinterpret_cast<const bf16x8*>(sh + (rowb + sc) * 8);
                acc[ns][0] = __builtin_amdgcn_mfma_f32_16x16x32_bf16(am, q0, acc[ns][0], 0, 0, 0);
                acc[ns][0] = __builtin_amdgcn_mfma_f32_16x16x32_bf16(ah, q3, acc[ns][0], 0, 0, 0);
                acc[ns][1] = __builtin_amdgcn_mfma_f32_16x16x32_bf16(am, q1, acc[ns][1], 0, 0, 0);
                acc[ns][1] = __builtin_amdgcn_mfma_f32_16x16x32_bf16(ah, q4, acc[ns][1], 0, 0, 0);
                acc[ns][2] = __builtin_amdgcn_mfma_f32_16x16x32_bf16(am, q2, acc[ns][2], 0, 0, 0);
                acc[ns][3] = __builtin_amdgcn_mfma_f32_16x16x32_bf16(ah, q5, acc[ns][3], 0, 0, 0);
            }
        };
        ld(0, A0, A1, A2, A3, A4, A5);
        ld(1, B0, B1, B2, B3, B4, B5);
        step(0, A0, A1, A2, A3, A4, A5);
        ld(2, A0, A1, A2, A3, A4, A5);
        step(1, B0, B1, B2, B3, B4, B5);
        ld(3, B0, B1, B2, B3, B4, B5);
        step(2, A0, A1, A2, A3, A4, A5);
        step(3, B0, B1, B2, B3, B4, B5);

        __syncthreads();   // all k-loop reads of sm complete -> sm reusable

        int fj = fsub * 16 + r;
        int chunk = fj >> 3, e = fj & 7;
        float b_r  = bih[fj] + bhh[fj];
        float b_z  = bih[128 + fj] + bhh[128 + fj];
        float bi_g = bih[256 + fj];
        float bh_g = bhh[256 + fj];
        #pragma unroll
        for (int ns = 0; ns < 4; ns++) {
            #pragma unroll
            for (int q = 0; q < 4; q++) {
                int row = ns * 16 + 4 * g + q;
                float rr2 = fsig(acc[ns][0][q] + b_r);
                float z   = fsig(acc[ns][1][q] + b_z);
                float cand = ftanh(acc[ns][2][q] + bi_g + rr2 * (acc[ns][3][q] + bh_g));
                float hv = bf2f((u32)sh[(row * 16 + (chunk ^ (row & 7))) * 8 + e]);
                float hn = (1.0f - z) * cand + z * hv;
                sm[(row * 16 + (chunk ^ (row & 7))) * 8 + e] = f2bf(hn);   // h_new into sm
            }
        }
    }
    __syncthreads();   // h_new tile (sm) complete; sh blend reads done

    if (do_gate) {
        if (wave >= 4) {
            int tid2 = tid - 256;
            #pragma unroll
            for (int rr = 0; rr < 4; rr++) {
                int row = rr * 16 + (tid2 >> 4);
                int c = tid2 & 15;
                int gn = node0 + row;
                if (gn < N) {
                    bf16x8 v = *reinterpret_cast<const bf16x8*>(sm + (row * 16 + (c ^ (row & 7))) * 8);
                    *reinterpret_cast<bf16x8*>(h16o + (size_t)gn * F + c * 8) = v;
                }
            }
        } else {
            int j = wave * 16 + r;
            f32x4 acc[4];
            #pragma unroll
            for (int ns = 0; ns < 4; ns++) acc[ns] = (f32x4){0, 0, 0, 0};
            #pragma unroll
            for (int k0 = 0; k0 < 4; k0++) {
                bf16x8 b = *reinterpret_cast<const bf16x8*>(pkgW1 + ((size_t)(wave * 4 + k0) * 64 + lane) * 8);
                int sc = (k0 * 4 + g) ^ (r & 7);
                #pragma unroll
                for (int ns = 0; ns < 4; ns++) {
                    bf16x8 a = *reinterpret_cast<const bf16x8*>(sm + ((ns * 16 + r) * 16 + sc) * 8);
                    acc[ns] = __builtin_amdgcn_mfma_f32_16x16x32_bf16(a, b, acc[ns], 0, 0, 0);
                }
            }
            float bb = gb1[j];
            #pragma unroll
            for (int ns = 0; ns < 4; ns++)
                #pragma unroll
                for (int q = 0; q < 4; q++) {
                    int row = ns * 16 + 4 * g + q;
                    sh[(row * 8 + ((j >> 3) ^ (row & 7))) * 8 + (j & 7)] = f2bf(softsign(acc[ns][q] + bb));
                }
        }
        __syncthreads();
        if (wave < 4) {
            int ns = wave;
            float partial[4] = {0.f, 0.f, 0.f, 0.f};
            #pragma unroll
            for (int fsub = 0; fsub < 2; fsub++) {
                f32x4 acc = {0, 0, 0, 0};
                #pragma unroll
                for (int k0 = 0; k0 < 2; k0++) {
                    bf16x8 b = *reinterpret_cast<const bf16x8*>(pkgW2 + ((size_t)(fsub * 2 + k0) * 64 + lane) * 8);
                    int sc = (k0 * 4 + g) ^ (r & 7);
                    bf16x8 a = *reinterpret_cast<const bf16x8*>(sh + ((ns * 16 + r) * 8 + sc) * 8);
                    acc = __builtin_amdgcn_mfma_f32_16x16x32_bf16(a, b, acc, 0, 0, 0);
                }
                float bb = gb2[fsub * 16 + r];
                float w3 = gW3[fsub * 16 + r];
                #pragma unroll
                for (int q = 0; q < 4; q++) partial[q] += softsign(acc[q] + bb) * w3;
            }
            #pragma unroll
            for (int o = 1; o < 16; o <<= 1)
                #pragma unroll
                for (int q = 0; q < 4; q++) partial[q] += __shfl_xor(partial[q], o);
            if (r == 0) {
                #pragma unroll
                for (int q = 0; q < 4; q++) {
                    int node = node0 + ns * 16 + 4 * g + q;
                    if (node < N) eg[node] = __expf(partial[q] + gb3[0]);
                }
            }
        }
    } else {
        #pragma unroll
        for (int rr = 0; rr < 2; rr++) {
            int row = rr * 32 + (tid >> 4);
            int c = tid & 15;
            int gn = node0 + row;
            if (gn < N) {
                bf16x8 v = *reinterpret_cast<const bf16x8*>(sm + (row * 16 + (c ^ (row & 7))) * 8);
                *reinterpret_cast<bf16x8*>(h16o + (size_t)gn * F + c * 8) = v;
            }
        }
    }
}

// ----------------------------------------------------------------------------
// Fused final attention + pooling, 64 nodes/block.
// v kept in REGISTERS (phase2/phase3 share the same lane->(row,col) mapping);
// softmax stats via shuffle + tiny per-wave partial arrays. No 32KB s_v tile:
// LDS ~35.5 KB -> 4 blocks/CU.
// ----------------------------------------------------------------------------
__global__ __launch_bounds__(256) void attn_fused(const u16* __restrict__ h16,
                                                  const u16* __restrict__ x16,
                                                  const u16* __restrict__ pkW1,  // 128 out, K=256
                                                  const float* __restrict__ b1,
                                                  const u16* __restrict__ pkW2,  // 128 out, K=128
                                                  const float* __restrict__ b2,
                                                  const u16* __restrict__ pkWj,  // 128 out, K=128
                                                  const float* __restrict__ bj,
                                                  float* __restrict__ pooled,
                                                  int N, int npg, int G) {
    __shared__ __align__(16) u16 smh[64 * 128];   // h -> ai1
    __shared__ __align__(16) u16 sx[64 * 128];
    __shared__ float s_mxp[4][64], s_sump[4][64];
    __shared__ float s_mx[64], s_rsum[64];
    __shared__ float s_pool[2][128];
    int tid = threadIdx.x;
    int wave = tid >> 6, lane = tid & 63, r = lane & 15, g = lane >> 4;
    int node0 = blockIdx.x * 64;

    s_pool[tid >> 7][tid & 127] = 0.f;

    #pragma unroll
    for (int rr = 0; rr < 4; rr++) {
        int row = rr * 16 + (tid >> 4);
        int c = tid & 15;
        int gn = node0 + row; if (gn >= N) gn = N - 1;
        bf16x8 vh = *reinterpret_cast<const bf16x8*>(h16 + (size_t)gn * F + c * 8);
        bf16x8 vx = *reinterpret_cast<const bf16x8*>(x16 + (size_t)gn * F + c * 8);
        int sc = c ^ (row & 7);
        *reinterpret_cast<bf16x8*>(smh + (row * 16 + sc) * 8) = vh;
        *reinterpret_cast<bf16x8*>(sx + (row * 16 + sc) * 8) = vx;
    }
    __syncthreads();

    // phase1: ai1 = ss([h|x] W1 + b1) -> registers
    float v1[2][4][4];
    #pragma unroll
    for (int fs = 0; fs < 2; fs++) {
        int fsub = wave * 2 + fs;
        int j = fsub * 16 + r;
        f32x4 acc[4];
        #pragma unroll
        for (int ns = 0; ns < 4; ns++) acc[ns] = (f32x4){0, 0, 0, 0};
        #pragma unroll
        for (int k0 = 0; k0 < 8; k0++) {
            bf16x8 b = *reinterpret_cast<const bf16x8*>(pkW1 + ((size_t)(fsub * 8 + k0) * 64 + lane) * 8);
            const u16* As = (k0 < 4) ? smh : sx;
            int sc = ((k0 & 3) * 4 + g) ^ (r & 7);
            #pragma unroll
            for (int ns = 0; ns < 4; ns++) {
                bf16x8 a = *reinterpret_cast<const bf16x8*>(As + ((ns * 16 + r) * 16 + sc) * 8);
                acc[ns] = __builtin_amdgcn_mfma_f32_16x16x32_bf16(a, b, acc[ns], 0, 0, 0);
            }
        }
        float bb = b1[j];
        #pragma unroll
        for (int ns = 0; ns < 4; ns++)
            #pragma unroll
            for (int q = 0; q < 4; q++) v1[fs][ns][q] = softsign(acc[ns][q] + bb);
    }
    __syncthreads();

    // scatter ai1 (bf16) into smh, swizzled
    #pragma unroll
    for (int fs = 0; fs < 2; fs++) {
        int j = (wave * 2 + fs) * 16 + r;
        #pragma unroll
        for (int ns = 0; ns < 4; ns++)
            #pragma unroll
            for (int q = 0; q < 4; q++) {
                int row = ns * 16 + 4 * g + q;
                smh[(row * 16 + ((j >> 3) ^ (row & 7))) * 8 + (j & 7)] = f2bf(v1[fs][ns][q]);
            }
    }
    __syncthreads();

    // phase2: v = ss(ai1 W2 + b2) -> registers v2
    float v2[2][4][4];
    #pragma unroll
    for (int fs = 0; fs < 2; fs++) {
        int fsub = wave * 2 + fs;
        int j = fsub * 16 + r;
        f32x4 acc[4];
        #pragma unroll
        for (int ns = 0; ns < 4; ns++) acc[ns] = (f32x4){0, 0, 0, 0};
        #pragma unroll
        for (int k0 = 0; k0 < 4; k0++) {
            bf16x8 b = *reinterpret_cast<const bf16x8*>(pkW2 + ((size_t)(fsub * 4 + k0) * 64 + lane) * 8);
            int sc = (k0 * 4 + g) ^ (r & 7);
            #pragma unroll
            for (int ns = 0; ns < 4; ns++) {
                bf16x8 a = *reinterpret_cast<const bf16x8*>(smh + ((ns * 16 + r) * 16 + sc) * 8);
                acc[ns] = __builtin_amdgcn_mfma_f32_16x16x32_bf16(a, b, acc[ns], 0, 0, 0);
            }
        }
        float bb = b2[j];
        #pragma unroll
        for (int ns = 0; ns < 4; ns++)
            #pragma unroll
            for (int q = 0; q < 4; q++) v2[fs][ns][q] = softsign(acc[ns][q] + bb);
    }

    // row max: in-register fsub merge -> 16-lane shuffle -> per-wave partial
    {
        float pm[4][4];
        #pragma unroll
        for (int ns = 0; ns < 4; ns++)
            #pragma unroll
            for (int q = 0; q < 4; q++) pm[ns][q] = fmaxf(v2[0][ns][q], v2[1][ns][q]);
        #pragma unroll
        for (int o = 1; o < 16; o <<= 1)
            #pragma unroll
            for (int ns = 0; ns < 4; ns++)
                #pragma unroll
                for (int q = 0; q < 4; q++) pm[ns][q] = fmaxf(pm[ns][q], __shfl_xor(pm[ns][q], o));
        if (r == 0)
            #pragma unroll
            for (int ns = 0; ns < 4; ns++)
                #pragma unroll
                for (int q = 0; q < 4; q++) s_mxp[wave][ns * 16 + 4 * g + q] = pm[ns][q];
    }
    __syncthreads();
    if (tid < 64)
        s_mx[tid] = fmaxf(fmaxf(s_mxp[0][tid], s_mxp[1][tid]),
                          fmaxf(s_mxp[2][tid], s_mxp[3][tid]));
    __syncthreads();

    // row expsum
    {
        float ps[4][4];
        #pragma unroll
        for (int ns = 0; ns < 4; ns++)
            #pragma unroll
            for (int q = 0; q < 4; q++) {
                float m = s_mx[ns * 16 + 4 * g + q];
                ps[ns][q] = __expf(v2[0][ns][q] - m) + __expf(v2[1][ns][q] - m);
            }
        #pragma unroll
        for (int o = 1; o < 16; o <<= 1)
            #pragma unroll
            for (int ns = 0; ns < 4; ns++)
                #pragma unroll
                for (int q = 0; q < 4; q++) ps[ns][q] += __shfl_xor(ps[ns][q], o);
        if (r == 0)
            #pragma unroll
            for (int ns = 0; ns < 4; ns++)
                #pragma unroll
                for (int q = 0; q < 4; q++) s_sump[wave][ns * 16 + 4 * g + q] = ps[ns][q];
    }
    __syncthreads();
    if (tid < 64)
        s_rsum[tid] = __fdividef(1.0f, s_sump[0][tid] + s_sump[1][tid] +
                                       s_sump[2][tid] + s_sump[3][tid]);
    __syncthreads();

    // phase3: aj = ss(x Wj + bj); node_out = softmax(v)*aj; pool
    int graph0 = node0 / npg;
    #pragma unroll
    for (int fs = 0; fs < 2; fs++) {
        int fsub = wave * 2 + fs;
        int j = fsub * 16 + r;
        f32x4 acc[4];
        #pragma unroll
        for (int ns = 0; ns < 4; ns++) acc[ns] = (f32x4){0, 0, 0, 0};
        #pragma unroll
        for (int k0 = 0; k0 < 4; k0++) {
            bf16x8 b = *reinterpret_cast<const bf16x8*>(pkWj + ((size_t)(fsub * 4 + k0) * 64 + lane) * 8);
            int sc = (k0 * 4 + g) ^ (r & 7);
            #pragma unroll
            for (int ns = 0; ns < 4; ns++) {
                bf16x8 a = *reinterpret_cast<const bf16x8*>(sx + ((ns * 16 + r) * 16 + sc) * 8);
                acc[ns] = __builtin_amdgcn_mfma_f32_16x16x32_bf16(a, b, acc[ns], 0, 0, 0);
            }
        }
        float bb = bj[j];
        float p0 = 0.f, p1 = 0.f;
        #pragma unroll
        for (int ns = 0; ns < 4; ns++)
            #pragma unroll
            for (int q = 0; q < 4; q++) {
                int row = ns * 16 + 4 * g + q;
                int node = node0 + row;
                if (node < N) {
                    float aj = softsign(acc[ns][q] + bb);
                    float attn = __expf(v2[fs][ns][q] - s_mx[row]) * s_rsum[row];
                    float val = attn * aj;
                    if (node / npg == graph0) p0 += val; else p1 += val;
                }
            }
        if (p0 != 0.f) atomicAdd(&s_pool[0][j], p0);
        if (p1 != 0.f) atomicAdd(&s_pool[1][j], p1);
    }
    __syncthreads();

    {
        int b_ = tid >> 7, colj = tid & 127;
        float v = s_pool[b_][colj];
        int gg = graph0 + b_;
        if (v != 0.f && gg < G) atomicAdd(&pooled[(size_t)gg * F + colj], v);
    }
}

// ----------------------------------------------------------------------------
// Out MLP (G blocks).
// ----------------------------------------------------------------------------
__global__ __launch_bounds__(128) void out_mlp(const float* __restrict__ pooled,
                                               const float* __restrict__ W1, const float* __restrict__ b1,
                                               const float* __restrict__ W2, const float* __restrict__ b2,
                                               const float* __restrict__ W3, const float* __restrict__ b3,
                                               float* __restrict__ out, int H1, int H2) {
    __shared__ float sp[128];
    __shared__ float s1[96];
    __shared__ float s2[64];
    int g = blockIdx.x, j = threadIdx.x;
    sp[j] = pooled[g * F + j];
    __syncthreads();
    if (j < H1) {
        float a = b1[j];
        for (int k = 0; k < 128; k++) a += sp[k] * W1[k * H1 + j];
        s1[j] = fmaxf(a, 0.f);
    }
    __syncthreads();
    if (j < H2) {
        float a = b2[j];
        for (int k = 0; k < H1; k++) a += s1[k] * W2[k * H2 + j];
        s2[j] = fmaxf(a, 0.f);
    }
    __syncthreads();
    if (j == 0) {
        float a = b3[0];
        for (int k = 0; k < H2; k++) a += s2[k] * W3[k];
        out[g] = a;
    }
}

// ----------------------------------------------------------------------------
extern "C" void kernel_launch(void* const* d_in, const int* in_sizes, int n_in,
                              void* d_out, int out_size, void* d_ws, size_t ws_size,
                              hipStream_t stream) {
    const float* x    = (const float*)d_in[0];
    const int*   ei   = (const int*)  d_in[1];
    const float* ea   = (const float*)d_in[2];
    const float* t    = (const float*)d_in[4];
    const float* gW1  = (const float*)d_in[5];
    const float* gb1  = (const float*)d_in[6];
    const float* gW2  = (const float*)d_in[7];
    const float* gb2  = (const float*)d_in[8];
    const float* gW3  = (const float*)d_in[9];
    const float* gb3  = (const float*)d_in[10];
    const float* Wih  = (const float*)d_in[11];
    const float* Whh  = (const float*)d_in[12];
    const float* bih  = (const float*)d_in[13];
    const float* bhh  = (const float*)d_in[14];
    const float* aiW1 = (const float*)d_in[15];
    const float* aib1 = (const float*)d_in[16];
    const float* aiW2 = (const float*)d_in[17];
    const float* aib2 = (const float*)d_in[18];
    const float* ajW  = (const float*)d_in[19];
    const float* ajb  = (const float*)d_in[20];
    const float* oW1  = (const float*)d_in[21];
    const float* ob1  = (const float*)d_in[22];
    const float* oW2  = (const float*)d_in[23];
    const float* ob2  = (const float*)d_in[24];
    const float* oW3  = (const float*)d_in[25];
    const float* ob3  = (const float*)d_in[26];
    float* out = (float*)d_out;

    const int N = in_sizes[0] / F;
    const int E = in_sizes[2];
    const int G = out_size;
    const int npg = N / G;
    const int H1 = 85, H2 = 64;
    const int Etot = 2 * E + N;

    char* w = (char*)d_ws;
    auto carve = [&](size_t bytes) {
        void* p = (void*)w;
        w += (bytes + 255) & ~(size_t)255;
        return p;
    };
    int*   deg     = (int*)  carve((size_t)N * 4);
    int*   row_ptr = (int*)  carve((size_t)(N + 1) * 4);
    int*   cursor  = (int*)  carve((size_t)N * 4);
    int*   bsum    = (int*)  carve((size_t)512 * 4);
    int*   col     = (int*)  carve((size_t)Etot * 4);
    float* eg      = (float*)carve((size_t)N * 4);
    u16*   m16     = (u16*)  carve((size_t)N * F * 2);
    u16*   h16A    = (u16*)  carve((size_t)N * F * 2);
    u16*   h16B    = (u16*)  carve((size_t)N * F * 2);
    u16*   x16     = (u16*)  carve((size_t)N * F * 2);
    u16*   pkWih   = (u16*)  carve((size_t)384 * F * 2);
    u16*   pkWhh   = (u16*)  carve((size_t)384 * F * 2);
    u16*   pkW1    = (u16*)  carve((size_t)128 * 256 * 2);
    u16*   pkW2    = (u16*)  carve((size_t)128 * 128 * 2);
    u16*   pkWj    = (u16*)  carve((size_t)128 * 128 * 2);
    u16*   pkgW1   = (u16*)  carve((size_t)64 * 128 * 2);
    u16*   pkgW2   = (u16*)  carve((size_t)32 * 64 * 2);
    float* pooled  = (float*)carve((size_t)G * F * 4);
    (void)ws_size; (void)n_in;

    // --- one-time packs + deg/pooled zero (single kernel) + x conversion ---
    int packTot = 174080 + N + G * F;
    pack_all<<<(packTot + 255) / 256, 256, 0, stream>>>(Wih, Whh, aiW1, aiW2, ajW, gW1, gW2,
                                                        pkWih, pkWhh, pkW1, pkW2, pkWj, pkgW1, pkgW2,
                                                        deg, pooled, N, G * F);
    int n4 = N * F / 4;
    conv_x<<<(n4 + 255) / 256, 256, 0, stream>>>(x, h16A, x16, n4);

    // --- CSR build (hierarchical scan) ---
    int eb = (Etot + 255) / 256;
    count_edges<<<eb, 256, 0, stream>>>(ei, ea, t, deg, E, N);
    int nbs = (N + 2047) / 2048;   // <= 256 for N <= 524288
    scan_partial<<<nbs, 256, 0, stream>>>(deg, bsum, N);
    scan_bsum<<<1, 256, 0, stream>>>(bsum, nbs);
    scan_final<<<nbs, 256, 0, stream>>>(deg, bsum, row_ptr, cursor, N, nbs);
    scatter_edges<<<eb, 256, 0, stream>>>(ei, ea, t, cursor, col, E, N);

    u16* h16c = h16A;
    u16* h16n = h16B;
    int nb64 = (N + 63) / 64;

    // gate for iteration 0 (h0 = x)
    gate_mfma<<<nb64, 256, 0, stream>>>(h16c, pkgW1, gb1, pkgW2, gb2, gW3, gb3, eg, N);

    for (int it = 0; it < PROP_ITER; it++) {
        aggregate<<<(N + 3) / 4, 256, 0, stream>>>(h16c, eg, row_ptr, col, m16, N);
        gru_fused<<<nb64, 512, 0, stream>>>(m16, h16c, pkWih, pkWhh, bih, bhh, h16n,
                                            pkgW1, gb1, pkgW2, gb2, gW3, gb3, eg,
                                            (it < PROP_ITER - 1) ? 1 : 0, N);
        u16* tmp = h16c; h16c = h16n; h16n = tmp;
    }

    // --- fused attention + pooling ---
    attn_fused<<<nb64, 256, 0, stream>>>(h16c, x16, pkW1, aib1, pkW2, aib2, pkWj, ajb,
                                         pooled, N, npg, G);
    out_mlp<<<G, 128, 0, stream>>>(pooled, oW1, ob1, oW2, ob2, oW3, ob3, out, H1, H2);
}